// Round 11
// baseline (307.369 us; speedup 1.0000x reference)
//
#include <hip/hip_runtime.h>
#include <hip/hip_bf16.h>

#define BATCH   4
#define SEQ     2048
#define DMODEL  1024
#define NHEADS  16
#define DHEAD   64
#define MROWS   (BATCH*SEQ)        // 8192
#define QKV_N   (3*DMODEL)         // 3072
#define NEG_BIG (-1.0e30f)
#define WS_NEED ((size_t)MROWS * 2*DMODEL * sizeof(__hip_bfloat16))  // 33,554,432
#define SCALE_Q 0.18033688011112042f   // 0.125 * log2(e); folded into Q

using bf16 = __hip_bfloat16;
typedef __attribute__((ext_vector_type(8))) short short8;
typedef __attribute__((ext_vector_type(4))) float floatx4;

// Static device buffers (module BSS; no hipMalloc)
__device__ __align__(16) unsigned short g_wqT[QKV_N * DMODEL];   // W_qkv^T bf16
__device__ __align__(16) unsigned short g_woT[DMODEL * DMODEL];  // W_out^T bf16

__device__ __forceinline__ unsigned short f2bf_rne(float f) {
    union { bf16 b; unsigned short u; } t;
    t.b = __float2bfloat16(f);
    return t.u;
}

// async global->LDS, 16B/lane; LDS dest = wave-uniform base + lane*16
__device__ __forceinline__ void gload_lds16(const void* g, void* l) {
    __builtin_amdgcn_global_load_lds(
        (const __attribute__((address_space(1))) unsigned*)g,
        (__attribute__((address_space(3))) unsigned*)l, 16, 0, 0);
}

// ---------------------------------------------------------------------------
// Weight transpose + cast: W fp32 [1024][N] -> dst bf16 [N][1024]
// ---------------------------------------------------------------------------
__global__ __launch_bounds__(256) void transcast_w(
    const float* __restrict__ W, int N, int which)
{
    unsigned short* dst = which ? g_woT : g_wqT;
    __shared__ unsigned short T[64][72];
    const int n0 = blockIdx.x * 64, k0 = blockIdx.y * 64;
    const int tid = threadIdx.x;
    const int r = tid >> 2, c0 = (tid & 3) * 16;

#pragma unroll
    for (int it = 0; it < 4; ++it) {
        const float4 v = *(const float4*)(W + (size_t)(k0 + r)*N + n0 + c0 + it*4);
        T[r][c0 + it*4 + 0] = f2bf_rne(v.x);
        T[r][c0 + it*4 + 1] = f2bf_rne(v.y);
        T[r][c0 + it*4 + 2] = f2bf_rne(v.z);
        T[r][c0 + it*4 + 3] = f2bf_rne(v.w);
    }
    __syncthreads();
    const int nr = tid >> 2, kc0 = (tid & 3) * 16;
#pragma unroll
    for (int it = 0; it < 2; ++it) {
        union { uint4 u4; unsigned short us[8]; } o;
#pragma unroll
        for (int j = 0; j < 8; j++) o.us[j] = T[kc0 + it*8 + j][nr];
        *(uint4*)(dst + (size_t)(n0 + nr)*DMODEL + k0 + kc0 + it*8) = o.u4;
    }
}

// ---------------------------------------------------------------------------
// MFMA GEMM, double-buffered LDS, ONE barrier per BK=32 slab.
// QKV_MODE=1: A = x fp32, cast in-register during staging (cast_x fused);
//             B = g_wqT; epilogue splits Q(pre-scaled)|K|VT.
// QKV_MODE=0: A = runtime bf16 (gload), B = g_woT, fp32 C + bias.
// Safety: prefetch into buf^1 at top of iter i is safe because the barrier
// at end of iter i-1 guarantees all reads of buf^1 completed.
// ---------------------------------------------------------------------------
template<int QKV_MODE>
__global__ __launch_bounds__(256) void gemm_mfma(
    const void* __restrict__ Av, const float* __restrict__ bias,
    void* __restrict__ C0, void* __restrict__ C1, void* __restrict__ C2)
{
    const unsigned short* BT = QKV_MODE ? g_wqT : g_woT;
    __shared__ alignas(16) unsigned short As[2][128*32];
    __shared__ alignas(16) unsigned short Bs[2][128*32];

    const int tid = threadIdx.x;
    const int bm = blockIdx.y, bn = blockIdx.x;
    const int w = tid >> 6, lane = tid & 63;
    const int m16 = lane & 15, quad = lane >> 4;
    const int m0 = (w & 1) * 64, n0w = (w >> 1) * 64;

    // B staging (gload): wave w covers rows [w*32, w*32+32)
    const int lrow  = lane >> 2;
    const int lcol  = (lane & 3) * 8;
    const unsigned short* bG = BT + (size_t)(bn*128 + w*32 + lrow)*DMODEL + lcol;
    // A fp32 staging (QKV): thread t -> row t>>1, k-half (t&1)*16
    const int aRow  = tid >> 1;
    const int aKh   = (tid & 1) * 16;
    const float* xA = (const float*)Av;
    const float* xP = QKV_MODE ? (xA + (size_t)(bm*128 + aRow)*DMODEL + aKh) : nullptr;
    // A bf16 staging (outproj): gload like B
    const unsigned short* aG = QKV_MODE ? nullptr
        : (const unsigned short*)Av + (size_t)(bm*128 + w*32 + lrow)*DMODEL + lcol;

    floatx4 acc[4][4];
#pragma unroll
    for (int i = 0; i < 4; i++)
#pragma unroll
        for (int j = 0; j < 4; j++) { acc[i][j][0]=0.f; acc[i][j][1]=0.f; acc[i][j][2]=0.f; acc[i][j][3]=0.f; }

    // ---- preload slab 0 into buf 0
    {
        char* bsL = (char*)&Bs[0][0] + w*2048;
        gload_lds16(bG,               bsL);
        gload_lds16(bG + 16*DMODEL,   bsL + 1024);
        if (QKV_MODE) {
            float4 a0 = *(const float4*)xP;
            float4 a1 = *(const float4*)(xP + 4);
            float4 a2 = *(const float4*)(xP + 8);
            float4 a3 = *(const float4*)(xP + 12);
            union { uint4 u4[2]; unsigned short us[16]; } t;
            t.us[0]=f2bf_rne(a0.x); t.us[1]=f2bf_rne(a0.y); t.us[2]=f2bf_rne(a0.z); t.us[3]=f2bf_rne(a0.w);
            t.us[4]=f2bf_rne(a1.x); t.us[5]=f2bf_rne(a1.y); t.us[6]=f2bf_rne(a1.z); t.us[7]=f2bf_rne(a1.w);
            t.us[8]=f2bf_rne(a2.x); t.us[9]=f2bf_rne(a2.y); t.us[10]=f2bf_rne(a2.z); t.us[11]=f2bf_rne(a2.w);
            t.us[12]=f2bf_rne(a3.x); t.us[13]=f2bf_rne(a3.y); t.us[14]=f2bf_rne(a3.z); t.us[15]=f2bf_rne(a3.w);
            *(uint4*)&As[0][aRow*32 + aKh]     = t.u4[0];
            *(uint4*)&As[0][aRow*32 + aKh + 8] = t.u4[1];
        } else {
            char* asL = (char*)&As[0][0] + w*2048;
            gload_lds16(aG,             asL);
            gload_lds16(aG + 16*DMODEL, asL + 1024);
        }
    }
    __syncthreads();

    for (int k0 = 0; k0 < DMODEL; k0 += 32) {
        const int buf = (k0 >> 5) & 1;
        const bool pre = (k0 + 32 < DMODEL);

        float4 a0, a1, a2, a3;
        if (pre) {
            // prefetch slab k0+32 into buf^1 (safe: prior barrier drained readers)
            char* bsL = (char*)&Bs[buf^1][0] + w*2048;
            gload_lds16(bG + k0 + 32,             bsL);
            gload_lds16(bG + 16*DMODEL + k0 + 32, bsL + 1024);
            if (QKV_MODE) {
                a0 = *(const float4*)(xP + k0 + 32);
                a1 = *(const float4*)(xP + k0 + 36);
                a2 = *(const float4*)(xP + k0 + 40);
                a3 = *(const float4*)(xP + k0 + 44);
            } else {
                char* asL = (char*)&As[buf^1][0] + w*2048;
                gload_lds16(aG + k0 + 32,             asL);
                gload_lds16(aG + 16*DMODEL + k0 + 32, asL + 1024);
            }
        }

        // ---- compute from buf
        short8 af[4], bf4[4];
#pragma unroll
        for (int i = 0; i < 4; ++i) af[i]  = *(const short8*)&As[buf][(m0 + i*16 + m16)*32 + quad*8];
#pragma unroll
        for (int j = 0; j < 4; ++j) bf4[j] = *(const short8*)&Bs[buf][(n0w + j*16 + m16)*32 + quad*8];
#pragma unroll
        for (int i = 0; i < 4; ++i)
#pragma unroll
            for (int j = 0; j < 4; ++j)
                acc[i][j] = __builtin_amdgcn_mfma_f32_16x16x32_bf16(af[i], bf4[j], acc[i][j], 0, 0, 0);

        if (pre && QKV_MODE) {
            union { uint4 u4[2]; unsigned short us[16]; } t;
            t.us[0]=f2bf_rne(a0.x); t.us[1]=f2bf_rne(a0.y); t.us[2]=f2bf_rne(a0.z); t.us[3]=f2bf_rne(a0.w);
            t.us[4]=f2bf_rne(a1.x); t.us[5]=f2bf_rne(a1.y); t.us[6]=f2bf_rne(a1.z); t.us[7]=f2bf_rne(a1.w);
            t.us[8]=f2bf_rne(a2.x); t.us[9]=f2bf_rne(a2.y); t.us[10]=f2bf_rne(a2.z); t.us[11]=f2bf_rne(a2.w);
            t.us[12]=f2bf_rne(a3.x); t.us[13]=f2bf_rne(a3.y); t.us[14]=f2bf_rne(a3.z); t.us[15]=f2bf_rne(a3.w);
            *(uint4*)&As[buf^1][aRow*32 + aKh]     = t.u4[0];
            *(uint4*)&As[buf^1][aRow*32 + aKh + 8] = t.u4[1];
        }
        __syncthreads();   // single barrier: publishes buf^1, protects buf reuse
    }

    const int gcolb = bn*128;
    float bv[4];
#pragma unroll
    for (int j = 0; j < 4; ++j) bv[j] = bias[gcolb + n0w + j*16 + m16];

    if (QKV_MODE) {
        const int seg = gcolb >> 10;           // 0=Q(scaled), 1=K, 2=V(transposed)
        if (seg < 2) {
            bf16* Cout = (bf16*)(seg ? C1 : C0);
            const float sc = seg ? 1.0f : SCALE_Q;
#pragma unroll
            for (int i = 0; i < 4; ++i)
#pragma unroll
                for (int r = 0; r < 4; ++r) {
                    const int gm = bm*128 + m0 + i*16 + quad*4 + r;
#pragma unroll
                    for (int j = 0; j < 4; ++j) {
                        const int cc = (gcolb + n0w + j*16 + m16) & 1023;
                        Cout[(size_t)gm*DMODEL + cc] = __float2bfloat16((acc[i][j][r] + bv[j]) * sc);
                    }
                }
        } else {
            bf16* VT = (bf16*)C2;
#pragma unroll
            for (int i = 0; i < 4; ++i) {
                const int gm0 = bm*128 + m0 + i*16 + quad*4;
                const int bb = gm0 >> 11, t0 = gm0 & 2047;
#pragma unroll
                for (int j = 0; j < 4; ++j) {
                    const int cv = (gcolb & 1023) + n0w + j*16 + m16;
                    const int hh = cv >> 6, dd = cv & 63;
                    union { unsigned long long u8; unsigned short us[4]; } o;
#pragma unroll
                    for (int r = 0; r < 4; ++r) o.us[r] = f2bf_rne(acc[i][j][r] + bv[j]);
                    *(unsigned long long*)(VT + ((size_t)((bb*NHEADS + hh)*DHEAD + dd))*SEQ + t0) = o.u8;
                }
            }
        }
    } else {
        float* Cout = (float*)C0;
#pragma unroll
        for (int i = 0; i < 4; ++i)
#pragma unroll
            for (int r = 0; r < 4; ++r) {
                const int gm = bm*128 + m0 + i*16 + quad*4 + r;
#pragma unroll
                for (int j = 0; j < 4; ++j) {
                    const int cc = (gcolb + n0w + j*16 + m16) & 1023;
                    Cout[(size_t)gm*DMODEL + cc] = acc[i][j][r] + bv[j];
                }
            }
    }
}

// ---------------------------------------------------------------------------
// MFMA flash attention v3 (unchanged from round 10 — passed)
// ---------------------------------------------------------------------------
__global__ __launch_bounds__(256, 2) void attn_mfma3(
    const bf16* __restrict__ Qg, const bf16* __restrict__ Kg,
    const bf16* __restrict__ VTg, bf16* __restrict__ Og)
{
    __shared__ alignas(16) unsigned short Kt[2][64][72];
    __shared__ alignas(16) unsigned short Vt[2][64][72];
    __shared__ alignas(16) unsigned short Ps[4][32][72];

    const int x = blockIdx.x;
    const int b = x >> 7, h = (x >> 3) & 15, p = x & 7;
    const int tid = threadIdx.x;
    const int w = tid >> 6, lane = tid & 63;
    const int m16 = lane & 15, quad = lane >> 4;
    const int sr = tid >> 2, sc0 = (tid & 3) * 8;
    const size_t bh = (size_t)(b*NHEADS + h);

    for (int seg = 0; seg < 2; ++seg) {
        const int qt  = seg ? (15 - p) : p;
        const int nkt = 2*qt + 2;
        const int qrow0 = qt*128 + w*32;

        short8 qf[2][2];
#pragma unroll
        for (int i = 0; i < 2; ++i)
#pragma unroll
            for (int c = 0; c < 2; ++c)
                qf[i][c] = *(const short8*)(Qg + (size_t)(b*SEQ + qrow0 + i*16 + m16)*DMODEL
                                            + h*DHEAD + c*32 + quad*8);

        floatx4 of[2][4];
        float mrow[2], lrow[2];
#pragma unroll
        for (int i = 0; i < 2; ++i) {
            mrow[i] = NEG_BIG; lrow[i] = 0.f;
#pragma unroll
            for (int nt = 0; nt < 4; ++nt) { of[i][nt][0]=0.f; of[i][nt][1]=0.f; of[i][nt][2]=0.f; of[i][nt][3]=0.f; }
        }

        {
            const bf16* kp = Kg  + (size_t)(b*SEQ + sr)*DMODEL + h*DHEAD + sc0;
            const bf16* vp = VTg + (bh*DHEAD + sr)*SEQ + sc0;
            const uint4 a0 = *(const uint4*)kp, a1 = *(const uint4*)(kp + 32);
            const uint4 b0 = *(const uint4*)vp, b1 = *(const uint4*)(vp + 32);
            __syncthreads();
            *(uint4*)&Kt[0][sr][sc0]      = a0;
            *(uint4*)&Kt[0][sr][sc0 + 32] = a1;
            *(uint4*)&Vt[0][sr][sc0]      = b0;
            *(uint4*)&Vt[0][sr][sc0 + 32] = b1;
            __syncthreads();
        }

        for (int kt = 0; kt < nkt; ++kt) {
            const int buf = kt & 1;
            const int k064 = kt * 64;
            const bool pre = (kt + 1 < nkt);
            uint4 kr0, kr1, vr0, vr1;
            if (pre) {
                const bf16* kp = Kg  + (size_t)(b*SEQ + k064 + 64 + sr)*DMODEL + h*DHEAD + sc0;
                const bf16* vp = VTg + (bh*DHEAD + sr)*SEQ + k064 + 64 + sc0;
                kr0 = *(const uint4*)kp; kr1 = *(const uint4*)(kp + 32);
                vr0 = *(const uint4*)vp; vr1 = *(const uint4*)(vp + 32);
            }

            floatx4 sf[2][4];
#pragma unroll
            for (int t4 = 0; t4 < 4; ++t4) {
                const short8 kf0 = *(const short8*)&Kt[buf][t4*16 + m16][quad*8];
                const short8 kf1 = *(const short8*)&Kt[buf][t4*16 + m16][32 + quad*8];
#pragma unroll
                for (int i = 0; i < 2; ++i) {
                    floatx4 a; a[0]=0.f; a[1]=0.f; a[2]=0.f; a[3]=0.f;
                    a = __builtin_amdgcn_mfma_f32_16x16x32_bf16(kf0, qf[i][0], a, 0, 0, 0);
                    a = __builtin_amdgcn_mfma_f32_16x16x32_bf16(kf1, qf[i][1], a, 0, 0, 0);
                    sf[i][t4] = a;
                }
            }

            const bool need_mask = (k064 + 63 > qrow0);
#pragma unroll
            for (int i = 0; i < 2; ++i) {
                if (need_mask) {
                    const int qg = qrow0 + i*16 + m16;
#pragma unroll
                    for (int t4 = 0; t4 < 4; ++t4)
#pragma unroll
                        for (int r = 0; r < 4; ++r)
                            if (k064 + t4*16 + quad*4 + r > qg) sf[i][t4][r] = NEG_BIG;
                }
                float mx = sf[i][0][0];
#pragma unroll
                for (int t4 = 0; t4 < 4; ++t4)
#pragma unroll
                    for (int r = 0; r < 4; ++r) mx = fmaxf(mx, sf[i][t4][r]);
                mx = fmaxf(mx, __shfl_xor(mx, 16));
                mx = fmaxf(mx, __shfl_xor(mx, 32));

                const float mnew  = fmaxf(mrow[i], mx);
                const float alpha = exp2f(mrow[i] - mnew);
                mrow[i] = mnew;

                float rs = 0.f;
#pragma unroll
                for (int t4 = 0; t4 < 4; ++t4) {
#pragma unroll
                    for (int r = 0; r < 4; ++r) {
                        const float pv = exp2f(sf[i][t4][r] - mnew);
                        sf[i][t4][r] = pv;
                        rs += pv;
                    }
                }
                rs += __shfl_xor(rs, 16);
                rs += __shfl_xor(rs, 32);
                lrow[i] = lrow[i]*alpha + rs;
#pragma unroll
                for (int nt = 0; nt < 4; ++nt)
#pragma unroll
                    for (int r = 0; r < 4; ++r) of[i][nt][r] *= alpha;

#pragma unroll
                for (int t4 = 0; t4 < 4; ++t4) {
                    union { unsigned long long u8; unsigned short us[4]; } o;
#pragma unroll
                    for (int r = 0; r < 4; ++r) o.us[r] = f2bf_rne(sf[i][t4][r]);
                    *(unsigned long long*)&Ps[w][i*16 + m16][t4*16 + quad*4] = o.u8;
                }
            }

            short8 pf[2][2];
#pragma unroll
            for (int i = 0; i < 2; ++i)
#pragma unroll
                for (int c = 0; c < 2; ++c)
                    pf[i][c] = *(const short8*)&Ps[w][i*16 + m16][c*32 + quad*8];
#pragma unroll
            for (int nt = 0; nt < 4; ++nt) {
                const short8 vf0 = *(const short8*)&Vt[buf][nt*16 + m16][quad*8];
                const short8 vf1 = *(const short8*)&Vt[buf][nt*16 + m16][32 + quad*8];
#pragma unroll
                for (int i = 0; i < 2; ++i) {
                    of[i][nt] = __builtin_amdgcn_mfma_f32_16x16x32_bf16(vf0, pf[i][0], of[i][nt], 0, 0, 0);
                    of[i][nt] = __builtin_amdgcn_mfma_f32_16x16x32_bf16(vf1, pf[i][1], of[i][nt], 0, 0, 0);
                }
            }

            if (pre) {
                *(uint4*)&Kt[buf^1][sr][sc0]      = kr0;
                *(uint4*)&Kt[buf^1][sr][sc0 + 32] = kr1;
                *(uint4*)&Vt[buf^1][sr][sc0]      = vr0;
                *(uint4*)&Vt[buf^1][sr][sc0 + 32] = vr1;
            }
            __syncthreads();
        }

#pragma unroll
        for (int i = 0; i < 2; ++i) {
            const float rl = 1.f / fmaxf(lrow[i], 1e-20f);
            const size_t rowbase = (size_t)(b*SEQ + qrow0 + i*16 + m16)*DMODEL + h*DHEAD;
#pragma unroll
            for (int nt = 0; nt < 4; ++nt) {
                union { unsigned long long u8; unsigned short us[4]; } o;
#pragma unroll
                for (int r = 0; r < 4; ++r) o.us[r] = f2bf_rne(of[i][nt][r] * rl);
                *(unsigned long long*)(Og + rowbase + nt*16 + quad*4) = o.u8;
            }
        }
    }
}

__global__ void diag_fill(float* out, int n, float val) {
    int i = blockIdx.x*blockDim.x + threadIdx.x;
    if (i < n) out[i] = val;
}

// ---------------------------------------------------------------------------
extern "C" void kernel_launch(void* const* d_in, const int* in_sizes, int n_in,
                              void* d_out, int out_size, void* d_ws, size_t ws_size,
                              hipStream_t stream) {
    const float* x     = (const float*)d_in[0];
    const float* W_qkv = (const float*)d_in[1];
    const float* b_qkv = (const float*)d_in[2];
    const float* W_out = (const float*)d_in[3];
    const float* b_out = (const float*)d_in[4];

    if (ws_size < WS_NEED) {
        const float val = 100.f + (float)(ws_size >> 20);
        diag_fill<<<(out_size + 255)/256, 256, 0, stream>>>((float*)d_out, out_size, val);
        return;
    }

    bf16* Qb  = (bf16*)d_out;                                // d_out lo: Q (pre-scaled)
    bf16* VTb = (bf16*)d_out + (size_t)MROWS*DMODEL;         // d_out hi: VT
    bf16* Kb  = (bf16*)d_ws;                                 // ws lo: K
    bf16* Ob  = (bf16*)d_ws + (size_t)MROWS*DMODEL;          // ws hi: O

    // 0) weight transpose+cast (x cast now fused into QKV GEMM)
    {
        dim3 gq(QKV_N/64, DMODEL/64);
        transcast_w<<<gq, 256, 0, stream>>>(W_qkv, QKV_N, 0);
        dim3 go(DMODEL/64, DMODEL/64);
        transcast_w<<<go, 256, 0, stream>>>(W_out, DMODEL, 1);
    }
    // 1) fused QKV projection (dbuf, fp32-A cast in staging)
    {
        dim3 g(QKV_N/128, MROWS/128);
        gemm_mfma<1><<<g, 256, 0, stream>>>(x, b_qkv, Qb, Kb, VTb);
    }
    // 2) flash attention v3
    {
        attn_mfma3<<<512, 256, 0, stream>>>(Qb, Kb, VTb, Ob);
    }
    // 3) output projection (dbuf, bf16 A via gload)
    {
        dim3 g(DMODEL/128, MROWS/128);
        gemm_mfma<0><<<g, 256, 0, stream>>>(Ob, b_out, d_out, nullptr, nullptr);
    }
}